// Round 8
// baseline (85.900 us; speedup 1.0000x reference)
//
#include <hip/hip_runtime.h>
#include <hip/hip_bf16.h>

#define V_   163842
#define K_   6
#define G_   5
#define N_   2
#define CIN  32
#define COUT 64
#define CG   160   // CIN * G_
#define TV   64    // vertices per block
#define CGP  168   // padded CG (row stride 336B -> ~2-way bank aliasing on b128 reads)
#define VTILES 2561          // ceil(V/TV)
#define GRIDX  (8 * 641)     // 8 xcd-slots * ceil(VTILES/4)

typedef __attribute__((ext_vector_type(8))) short bf16x8;
typedef __attribute__((ext_vector_type(4))) float f32x4;
typedef __attribute__((ext_vector_type(2))) float f32x2;

__device__ __forceinline__ float bf2f(unsigned int u16) {
  union { unsigned int u; float f; } c; c.u = u16 << 16; return c.f;
}
__device__ __forceinline__ unsigned short f2bf(float f) {
  union { float f; unsigned int u; } c; c.f = f;
  unsigned int r = c.u + 0x7fffu + ((c.u >> 16) & 1u);
  return (unsigned short)(r >> 16);
}

// x[n][c][v] fp32 -> xtn[n][v][c] bf16: two per-batch tables of 64B records.
// Each table is 10.5 MB; n-pinned blocks on 4 XCDs have 16 MB aggregate L2 -> table resident.
__global__ __launch_bounds__(256) void transpose_kernel(const float* __restrict__ x,
                                                        unsigned short* __restrict__ xtn) {
  int v = blockIdx.x * 256 + threadIdx.x;
  if (v >= V_) return;
#pragma unroll
  for (int n = 0; n < N_; ++n) {
    const float* xp = x + (size_t)n * CIN * V_ + v;
    unsigned int words[CIN / 2];
#pragma unroll
    for (int w = 0; w < CIN / 2; ++w) {
      float a = xp[(size_t)(2 * w) * V_];
      float b = xp[(size_t)(2 * w + 1) * V_];
      words[w] = (unsigned int)f2bf(a) | ((unsigned int)f2bf(b) << 16);
    }
    uint4* dst = (uint4*)(xtn + ((size_t)n * V_ + v) * CIN);
#pragma unroll
    for (int i = 0; i < 4; ++i)
      dst[i] = make_uint4(words[4 * i], words[4 * i + 1], words[4 * i + 2], words[4 * i + 3]);
  }
}

__global__ void icoconv_kernel(
    const unsigned short* __restrict__ xtn,
    const int* __restrict__ nbr,
    const float* __restrict__ gw,
    const float* __restrict__ convw,
    const float* __restrict__ convb,
    float* __restrict__ out) {
  __shared__ int   idx_s[TV * K_];
  __shared__ float gw_s[TV * G_ * K_];
  __shared__ __align__(16) unsigned short G_s[TV][CGP];
  __shared__ float pad_s[4096];   // occupancy pad: total LDS ~47KB -> 3 blocks/CU (R3 regime)

  const int bid   = blockIdx.x;
  const int slot  = bid & 7;                  // bid%8 -> XCD (round-robin dispatch)
  const int n     = slot >> 2;                // n=0 on XCD0-3, n=1 on XCD4-7
  const int vtile = (bid >> 3) * 4 + (slot & 3);
  if (vtile >= VTILES) return;                // uniform across block, before any barrier
  const int v0 = vtile * TV;

  const int t = threadIdx.x;

  // ---- stage 0: idx + grad_w cooperative loads (R3 ordering) ----
  for (int i = t; i < TV * K_; i += 256) {
    int gi = v0 * K_ + i;
    idx_s[i] = (gi < V_ * K_) ? nbr[gi] : 0;
  }
  for (int i = t; i < TV * G_ * K_; i += 256) {
    int gi = v0 * G_ * K_ + i;
    gw_s[i] = (gi < V_ * G_ * K_) ? gw[gi] : 0.0f;  // zero weights => zero grads for tail v
  }
  __syncthreads();
  if (idx_s[0] == -1) pad_s[t] = 0.0f;        // never true (idx>=0); keeps pad_s alive

  // ---- stage 1: per-pass gather + grads (R3 structure), bf16 tile to LDS ----
  // thread t -> c-pair cp = t&15 (c = 2cp, 2cp+1), vertex rows vl = (t>>4) + 16*pass
  const int cp = t & 15;
  const int vb = t >> 4;
  const unsigned short* tab = xtn + (size_t)n * V_ * CIN;
#pragma unroll
  for (int pass = 0; pass < 4; ++pass) {
    const int vl = vb + pass * 16;

    int j[K_];
#pragma unroll
    for (int k = 0; k < K_; ++k) j[k] = idx_s[vl * K_ + k];
    unsigned int u[K_];
#pragma unroll
    for (int k = 0; k < K_; ++k)
      u[k] = *(const unsigned int*)(tab + (size_t)j[k] * CIN + 2 * cp);

    f32x2 acc[G_];                             // (c even, c odd) per g
#pragma unroll
    for (int g = 0; g < G_; ++g) acc[g] = (f32x2){0.0f, 0.0f};

#pragma unroll
    for (int k = 0; k < K_; ++k) {
      const f32x2 xv = {bf2f(u[k] & 0xffffu), bf2f(u[k] >> 16)};
#pragma unroll
      for (int g = 0; g < G_; ++g) {
        const float w = gw_s[vl * (G_ * K_) + g * K_ + k];
        acc[g] += xv * (f32x2){w, w};          // v_pk_fma_f32
      }
    }
    // pack 10 bf16 (c=2cp: g0..4, c=2cp+1: g0..4) -> 5 dwords at cg = 10*cp
    unsigned int* dst = (unsigned int*)&G_s[vl][cp * 10];
    unsigned short h[10];
#pragma unroll
    for (int c01 = 0; c01 < 2; ++c01)
#pragma unroll
      for (int g = 0; g < G_; ++g) h[c01 * G_ + g] = f2bf(acc[g][c01]);
#pragma unroll
    for (int i = 0; i < 5; ++i)
      dst[i] = (unsigned int)h[2 * i] | ((unsigned int)h[2 * i + 1] << 16);
  }
  __syncthreads();

  // ---- stage 2: out[n][64o x 64v] = W(64x160) @ G(160x64) + b, via MFMA 16x16x32 ----
  const int lane = t & 63;
  const int wave = t >> 6;
  const int o0   = wave * 16;
  const int row  = lane & 15;   // A row (o), B col (v), D col (v)
  const int kg   = lane >> 4;   // k-group: 8 contiguous K per 16-lane group

  bf16x8 afrag[5];
#pragma unroll
  for (int ks = 0; ks < 5; ++ks) {
    const float* wp = convw + (size_t)(o0 + row) * CG + ks * 32 + kg * 8;
    const float4 lo = *(const float4*)wp;
    const float4 hi = *(const float4*)(wp + 4);
    bf16x8 a;
    a[0] = (short)f2bf(lo.x); a[1] = (short)f2bf(lo.y);
    a[2] = (short)f2bf(lo.z); a[3] = (short)f2bf(lo.w);
    a[4] = (short)f2bf(hi.x); a[5] = (short)f2bf(hi.y);
    a[6] = (short)f2bf(hi.z); a[7] = (short)f2bf(hi.w);
    afrag[ks] = a;
  }
  float bias[4];
#pragma unroll
  for (int r = 0; r < 4; ++r) bias[r] = convb[o0 + kg * 4 + r];

#pragma unroll
  for (int vt = 0; vt < 4; ++vt) {
    f32x4 acc = {bias[0], bias[1], bias[2], bias[3]};
#pragma unroll
    for (int ks = 0; ks < 5; ++ks) {
      bf16x8 bfrag = *(const bf16x8*)(&G_s[vt * 16 + row][ks * 32 + kg * 8]);
      acc = __builtin_amdgcn_mfma_f32_16x16x32_bf16(afrag[ks], bfrag, acc, 0, 0, 0);
    }
    const int v = v0 + vt * 16 + row;
    if (v < V_) {
#pragma unroll
      for (int r = 0; r < 4; ++r)
        out[(size_t)(n * COUT + o0 + kg * 4 + r) * V_ + v] = acc[r];
    }
  }
}

extern "C" void kernel_launch(void* const* d_in, const int* in_sizes, int n_in,
                              void* d_out, int out_size, void* d_ws, size_t ws_size,
                              hipStream_t stream) {
  const float* x     = (const float*)d_in[0];
  const int*   nbr   = (const int*)d_in[1];
  const float* gw    = (const float*)d_in[2];
  const float* convw = (const float*)d_in[3];
  const float* convb = (const float*)d_in[4];
  float* out = (float*)d_out;
  unsigned short* xtn = (unsigned short*)d_ws;  // 2 tables of V*32 bf16 = 21 MB total

  transpose_kernel<<<(V_ + 255) / 256, 256, 0, stream>>>(x, xtn);
  icoconv_kernel<<<GRIDX, 256, 0, stream>>>(xtn, nbr, gw, convw, convb, out);
}

// Round 9
// 71.288 us; speedup vs baseline: 1.2050x; 1.2050x over previous
//
#include <hip/hip_runtime.h>
#include <hip/hip_bf16.h>

#define V_   163842
#define K_   6
#define G_   5
#define N_   2
#define CIN  32
#define COUT 64
#define CG   160   // CIN * G_
#define TV   64    // vertices per block
#define CGP  168   // padded CG (row stride 336B -> ~2-way bank aliasing on b128 reads)

typedef __attribute__((ext_vector_type(8))) short bf16x8;
typedef __attribute__((ext_vector_type(4))) float f32x4;
typedef __attribute__((ext_vector_type(2))) float f32x2;

__device__ __forceinline__ float bf2f(unsigned int u16) {
  union { unsigned int u; float f; } c; c.u = u16 << 16; return c.f;
}
__device__ __forceinline__ unsigned short f2bf(float f) {
  union { float f; unsigned int u; } c; c.f = f;
  unsigned int r = c.u + 0x7fffu + ((c.u >> 16) & 1u);
  return (unsigned short)(r >> 16);
}

// x[n][c][v] fp32 -> xt[v][c][n] bf16 (both batches interleaved: 128B per vertex,
// so each gather of a vertex hits ONE cache-line pair instead of two lines 10MB apart)
__global__ __launch_bounds__(256) void transpose_kernel(const float* __restrict__ x,
                                                        unsigned short* __restrict__ xt) {
  int v = blockIdx.x * 256 + threadIdx.x;
  if (v >= V_) return;
  const float* x0 = x + v;                       // n=0, c-major stride V_
  const float* x1 = x + (size_t)CIN * V_ + v;    // n=1
  unsigned int words[CIN];
#pragma unroll
  for (int c = 0; c < CIN; ++c) {
    float a = x0[(size_t)c * V_];
    float b = x1[(size_t)c * V_];
    words[c] = (unsigned int)f2bf(a) | ((unsigned int)f2bf(b) << 16);  // (n0, n1)
  }
  uint4* dst = (uint4*)(xt + (size_t)v * (2 * CIN));
#pragma unroll
  for (int i = 0; i < 8; ++i)
    dst[i] = make_uint4(words[4 * i], words[4 * i + 1], words[4 * i + 2], words[4 * i + 3]);
}

__global__ __launch_bounds__(256, 4) void icoconv_kernel(
    const unsigned short* __restrict__ xt,
    const int* __restrict__ nbr,
    const float* __restrict__ gw,
    const float* __restrict__ convw,
    const float* __restrict__ convb,
    float* __restrict__ out) {
  __shared__ float gw_s[TV * G_ * K_];
  __shared__ __align__(16) unsigned short G_s[N_][TV][CGP];

  const int t  = threadIdx.x;
  const int v0 = blockIdx.x * TV;
  const int cp = t & 15;          // channel pair: c = 2cp, 2cp+1
  const int vb = t >> 4;          // vertex row base within 16-row pass groups

  // ---- issue gw_s cooperative load FIRST (overlaps with pass-0 gather flight) ----
  for (int i = t; i < TV * G_ * K_; i += 256) {
    int gi = v0 * G_ * K_ + i;
    gw_s[i] = (gi < V_ * G_ * K_) ? gw[gi] : 0.0f;  // zero weights => zero grads for tail v
  }

  // ---- prologue: per-thread idx load + gather issue for pass 0 ----
  // idx read directly (16 lanes/group share the same 24B -> L1 broadcast); no idx LDS.
  uint2 u[2][K_];
  {
    const int vv = min(v0 + vb, V_ - 1);
    const int64_t base = (int64_t)vv * K_;
#pragma unroll
    for (int k = 0; k < K_; ++k) {
      const int j = nbr[base + k];
      u[0][k] = *(const uint2*)(xt + (size_t)j * (2 * CIN) + 4 * cp);
    }
  }

  __syncthreads();   // gw_s ready (also drains pass-0 gathers, which had load-time to fly)

  // ---- stage 1: software-pipelined passes: issue p+1 gathers, consume p ----
#pragma unroll
  for (int pass = 0; pass < 4; ++pass) {
    if (pass < 3) {
      const int vv = min(v0 + vb + (pass + 1) * 16, V_ - 1);
      const int64_t base = (int64_t)vv * K_;
#pragma unroll
      for (int k = 0; k < K_; ++k) {
        const int j = nbr[base + k];
        u[(pass + 1) & 1][k] = *(const uint2*)(xt + (size_t)j * (2 * CIN) + 4 * cp);
      }
    }

    const int vl = vb + pass * 16;
    f32x2 acc[N_][G_];   // [n][g] over c01 (c even, c odd)
#pragma unroll
    for (int n = 0; n < N_; ++n)
#pragma unroll
      for (int g = 0; g < G_; ++g) acc[n][g] = (f32x2){0.0f, 0.0f};

#pragma unroll
    for (int k = 0; k < K_; ++k) {
      const uint2 uu = u[pass & 1][k];
      const f32x2 x0 = {bf2f(uu.x & 0xffffu), bf2f(uu.y & 0xffffu)};  // n0
      const f32x2 x1 = {bf2f(uu.x >> 16),     bf2f(uu.y >> 16)};      // n1
#pragma unroll
      for (int g = 0; g < G_; ++g) {
        const float w = gw_s[vl * (G_ * K_) + g * K_ + k];
        const f32x2 w2 = {w, w};
        acc[0][g] += x0 * w2;   // v_pk_fma_f32
        acc[1][g] += x1 * w2;
      }
    }
    // pack 10 bf16 (c=2cp: g0..4, c=2cp+1: g0..4) -> 5 dwords at cg = 10*cp
#pragma unroll
    for (int n = 0; n < N_; ++n) {
      unsigned int* dst = (unsigned int*)&G_s[n][vl][cp * 10];
      unsigned short h[10];
#pragma unroll
      for (int c01 = 0; c01 < 2; ++c01)
#pragma unroll
        for (int g = 0; g < G_; ++g) h[c01 * G_ + g] = f2bf(acc[n][g][c01]);
#pragma unroll
      for (int i = 0; i < 5; ++i)
        dst[i] = (unsigned int)h[2 * i] | ((unsigned int)h[2 * i + 1] << 16);
    }
  }
  __syncthreads();

  // ---- stage 2: out[64o x 64v] = W(64x160) @ G(160x64) + b, via MFMA 16x16x32 ----
  const int lane = t & 63;
  const int wave = t >> 6;
  const int o0   = wave * 16;
  const int row  = lane & 15;   // A row (o), B col (v), D col (v)
  const int kg   = lane >> 4;   // k-group: 8 contiguous K per 16-lane group

  bf16x8 afrag[5];
#pragma unroll
  for (int ks = 0; ks < 5; ++ks) {
    const float* wp = convw + (size_t)(o0 + row) * CG + ks * 32 + kg * 8;
    const float4 lo = *(const float4*)wp;
    const float4 hi = *(const float4*)(wp + 4);
    bf16x8 a;
    a[0] = (short)f2bf(lo.x); a[1] = (short)f2bf(lo.y);
    a[2] = (short)f2bf(lo.z); a[3] = (short)f2bf(lo.w);
    a[4] = (short)f2bf(hi.x); a[5] = (short)f2bf(hi.y);
    a[6] = (short)f2bf(hi.z); a[7] = (short)f2bf(hi.w);
    afrag[ks] = a;
  }
  float bias[4];
#pragma unroll
  for (int r = 0; r < 4; ++r) bias[r] = convb[o0 + kg * 4 + r];

#pragma unroll
  for (int n = 0; n < N_; ++n) {
#pragma unroll
    for (int vt = 0; vt < 4; ++vt) {
      f32x4 acc = {bias[0], bias[1], bias[2], bias[3]};
#pragma unroll
      for (int ks = 0; ks < 5; ++ks) {
        bf16x8 bfrag = *(const bf16x8*)(&G_s[n][vt * 16 + row][ks * 32 + kg * 8]);
        acc = __builtin_amdgcn_mfma_f32_16x16x32_bf16(afrag[ks], bfrag, acc, 0, 0, 0);
      }
      const int v = v0 + vt * 16 + row;
      if (v < V_) {
#pragma unroll
        for (int r = 0; r < 4; ++r)
          out[(size_t)(n * COUT + o0 + kg * 4 + r) * V_ + v] = acc[r];
      }
    }
  }
}

extern "C" void kernel_launch(void* const* d_in, const int* in_sizes, int n_in,
                              void* d_out, int out_size, void* d_ws, size_t ws_size,
                              hipStream_t stream) {
  const float* x     = (const float*)d_in[0];
  const int*   nbr   = (const int*)d_in[1];
  const float* gw    = (const float*)d_in[2];
  const float* convw = (const float*)d_in[3];
  const float* convb = (const float*)d_in[4];
  float* out = (float*)d_out;
  unsigned short* xt = (unsigned short*)d_ws;  // V*64 bf16 (n-interleaved) = 21 MB

  transpose_kernel<<<(V_ + 255) / 256, 256, 0, stream>>>(x, xt);

  const int nblk = (V_ + TV - 1) / TV;
  icoconv_kernel<<<nblk, 256, 0, stream>>>(xt, nbr, gw, convw, convb, out);
}

// Round 10
// 69.091 us; speedup vs baseline: 1.2433x; 1.0318x over previous
//
#include <hip/hip_runtime.h>
#include <hip/hip_bf16.h>

#define V_   163842
#define K_   6
#define G_   5
#define N_   2
#define CIN  32
#define COUT 64
#define CG   160   // CIN * G_
#define TV   64    // vertices per block
#define CGP  168   // padded CG (row stride 336B -> ~2-way bank aliasing on b128 reads)

typedef __attribute__((ext_vector_type(8))) short bf16x8;
typedef __attribute__((ext_vector_type(4))) float f32x4;
typedef __attribute__((ext_vector_type(2))) float f32x2;

__device__ __forceinline__ float bf2f(unsigned int u16) {
  union { unsigned int u; float f; } c; c.u = u16 << 16; return c.f;
}
__device__ __forceinline__ unsigned short f2bf(float f) {
  union { float f; unsigned int u; } c; c.f = f;
  unsigned int r = c.u + 0x7fffu + ((c.u >> 16) & 1u);
  return (unsigned short)(r >> 16);
}

// x[n][c][v] fp32 -> xt[v][c][n] bf16 (both batches interleaved: 128B per vertex record)
__global__ __launch_bounds__(256) void transpose_kernel(const float* __restrict__ x,
                                                        unsigned short* __restrict__ xt) {
  int v = blockIdx.x * 256 + threadIdx.x;
  if (v >= V_) return;
  const float* x0 = x + v;                       // n=0, c-major stride V_
  const float* x1 = x + (size_t)CIN * V_ + v;    // n=1
  unsigned int words[CIN];
#pragma unroll
  for (int c = 0; c < CIN; ++c) {
    float a = x0[(size_t)c * V_];
    float b = x1[(size_t)c * V_];
    words[c] = (unsigned int)f2bf(a) | ((unsigned int)f2bf(b) << 16);  // (n0, n1)
  }
  uint4* dst = (uint4*)(xt + (size_t)v * (2 * CIN));
#pragma unroll
  for (int i = 0; i < 8; ++i)
    dst[i] = make_uint4(words[4 * i], words[4 * i + 1], words[4 * i + 2], words[4 * i + 3]);
}

__global__ __launch_bounds__(256, 4) void icoconv_kernel(
    const unsigned short* __restrict__ xt,
    const int* __restrict__ nbr,
    const float* __restrict__ gw,
    const float* __restrict__ convw,
    const float* __restrict__ convb,
    float* __restrict__ out) {
  __shared__ float gw_s[TV * G_ * K_];
  __shared__ __align__(16) unsigned short G_s[N_][TV][CGP];

  const int t  = threadIdx.x;
  const int v0 = blockIdx.x * TV;
  const int lg = t & 7;           // lane-group index: 8 lanes cover one 128B record
  const int vb = t >> 3;          // vertex row base: 32 rows per pass

  // ---- issue gw_s cooperative load FIRST (overlaps with pass-0 gather flight) ----
  for (int i = t; i < TV * G_ * K_; i += 256) {
    int gi = v0 * G_ * K_ + i;
    gw_s[i] = (gi < V_ * G_ * K_) ? gw[gi] : 0.0f;  // zero weights => zero grads for tail v
  }

  // ---- prologue: per-thread idx load + dwordx4 gather issue for pass 0 ----
  // lane lg reads bytes [16lg,16lg+16) of the record: channels 4lg..4lg+3, both n
  uint4 u[2][K_];
  {
    const int vv = min(v0 + vb, V_ - 1);
    const int64_t base = (int64_t)vv * K_;
#pragma unroll
    for (int k = 0; k < K_; ++k) {
      const int j = nbr[base + k];
      u[0][k] = *(const uint4*)(xt + (size_t)j * (2 * CIN) + 8 * lg);
    }
  }

  __syncthreads();   // gw_s ready; pass-0 gathers have been in flight meanwhile

  // ---- stage 1: 2 software-pipelined passes (32 rows each) ----
#pragma unroll
  for (int pass = 0; pass < 2; ++pass) {
    if (pass == 0) {
      const int vv = min(v0 + vb + 32, V_ - 1);
      const int64_t base = (int64_t)vv * K_;
#pragma unroll
      for (int k = 0; k < K_; ++k) {
        const int j = nbr[base + k];
        u[1][k] = *(const uint4*)(xt + (size_t)j * (2 * CIN) + 8 * lg);
      }
    }

    const int vl = vb + pass * 32;
    // acc[n][p][g]: p = channel pair within this lane's 4 channels (c = 4lg+2p, 4lg+2p+1)
    f32x2 acc[N_][2][G_];
#pragma unroll
    for (int n = 0; n < N_; ++n)
#pragma unroll
      for (int p = 0; p < 2; ++p)
#pragma unroll
        for (int g = 0; g < G_; ++g) acc[n][p][g] = (f32x2){0.0f, 0.0f};

#pragma unroll
    for (int k = 0; k < K_; ++k) {
      const uint4 uu = u[pass][k];
      // word ci holds channel 4lg+ci: low16 = n0, high16 = n1
      const f32x2 x0a = {bf2f(uu.x & 0xffffu), bf2f(uu.y & 0xffffu)};  // n0, c pair 0
      const f32x2 x0b = {bf2f(uu.z & 0xffffu), bf2f(uu.w & 0xffffu)};  // n0, c pair 1
      const f32x2 x1a = {bf2f(uu.x >> 16),     bf2f(uu.y >> 16)};      // n1, c pair 0
      const f32x2 x1b = {bf2f(uu.z >> 16),     bf2f(uu.w >> 16)};      // n1, c pair 1
#pragma unroll
      for (int g = 0; g < G_; ++g) {
        const float w = gw_s[vl * (G_ * K_) + g * K_ + k];
        const f32x2 w2 = {w, w};
        acc[0][0][g] += x0a * w2;   // v_pk_fma_f32
        acc[0][1][g] += x0b * w2;
        acc[1][0][g] += x1a * w2;
        acc[1][1][g] += x1b * w2;
      }
    }
    // pack: channel pair p -> 10 bf16 -> 5 dwords at cg = 20lg + 10p (cg = c*5+g, c-major)
#pragma unroll
    for (int n = 0; n < N_; ++n) {
#pragma unroll
      for (int p = 0; p < 2; ++p) {
        unsigned int* dst = (unsigned int*)&G_s[n][vl][20 * lg + 10 * p];
        unsigned short h[10];
#pragma unroll
        for (int c01 = 0; c01 < 2; ++c01)
#pragma unroll
          for (int g = 0; g < G_; ++g) h[c01 * G_ + g] = f2bf(acc[n][p][g][c01]);
#pragma unroll
        for (int i = 0; i < 5; ++i)
          dst[i] = (unsigned int)h[2 * i] | ((unsigned int)h[2 * i + 1] << 16);
      }
    }
  }
  __syncthreads();

  // ---- stage 2: out[64o x 64v] = W(64x160) @ G(160x64) + b, via MFMA 16x16x32 ----
  const int lane = t & 63;
  const int wave = t >> 6;
  const int o0   = wave * 16;
  const int row  = lane & 15;   // A row (o), B col (v), D col (v)
  const int kg   = lane >> 4;   // k-group: 8 contiguous K per 16-lane group

  bf16x8 afrag[5];
#pragma unroll
  for (int ks = 0; ks < 5; ++ks) {
    const float* wp = convw + (size_t)(o0 + row) * CG + ks * 32 + kg * 8;
    const float4 lo = *(const float4*)wp;
    const float4 hi = *(const float4*)(wp + 4);
    bf16x8 a;
    a[0] = (short)f2bf(lo.x); a[1] = (short)f2bf(lo.y);
    a[2] = (short)f2bf(lo.z); a[3] = (short)f2bf(lo.w);
    a[4] = (short)f2bf(hi.x); a[5] = (short)f2bf(hi.y);
    a[6] = (short)f2bf(hi.z); a[7] = (short)f2bf(hi.w);
    afrag[ks] = a;
  }
  float bias[4];
#pragma unroll
  for (int r = 0; r < 4; ++r) bias[r] = convb[o0 + kg * 4 + r];

#pragma unroll
  for (int n = 0; n < N_; ++n) {
#pragma unroll
    for (int vt = 0; vt < 4; ++vt) {
      f32x4 acc = {bias[0], bias[1], bias[2], bias[3]};
#pragma unroll
      for (int ks = 0; ks < 5; ++ks) {
        bf16x8 bfrag = *(const bf16x8*)(&G_s[n][vt * 16 + row][ks * 32 + kg * 8]);
        acc = __builtin_amdgcn_mfma_f32_16x16x32_bf16(afrag[ks], bfrag, acc, 0, 0, 0);
      }
      const int v = v0 + vt * 16 + row;
      if (v < V_) {
#pragma unroll
        for (int r = 0; r < 4; ++r)
          out[(size_t)(n * COUT + o0 + kg * 4 + r) * V_ + v] = acc[r];
      }
    }
  }
}

extern "C" void kernel_launch(void* const* d_in, const int* in_sizes, int n_in,
                              void* d_out, int out_size, void* d_ws, size_t ws_size,
                              hipStream_t stream) {
  const float* x     = (const float*)d_in[0];
  const int*   nbr   = (const int*)d_in[1];
  const float* gw    = (const float*)d_in[2];
  const float* convw = (const float*)d_in[3];
  const float* convb = (const float*)d_in[4];
  float* out = (float*)d_out;
  unsigned short* xt = (unsigned short*)d_ws;  // V*64 bf16 (n-interleaved) = 21 MB

  transpose_kernel<<<(V_ + 255) / 256, 256, 0, stream>>>(x, xt);

  const int nblk = (V_ + TV - 1) / TV;
  icoconv_kernel<<<nblk, 256, 0, stream>>>(xt, nbr, gw, convw, convb, out);
}